// Round 15
// baseline (84.257 us; speedup 1.0000x reference)
//
#include <hip/hip_runtime.h>
#include <math.h>

#define NATOMS    128
#define NSEG      7875     // segments: i in [0,124], j in [i+2,126]
#define NSEG_PAD  8192
#define OUT_PER_B 16256    // 128*127 (row-major, diagonal skipped)
#define PTAB_PAD  16384    // padded so the register prefetch never reads OOB
#define BLOCK     512
#define NPF       32       // prefetched ptab entries per thread (32*512 = 16384)
#define NSF       16       // prefetched gseg entries per thread (16*512 = 8192)

typedef float v2f __attribute__((ext_vector_type(2)));
__device__ __forceinline__ v2f mk2(float a, float b) { v2f r; r.x = a; r.y = b; return r; }

struct P3 { v2f x, y, z; };
__device__ __forceinline__ P3 psub(P3 a, P3 b) { return {a.x - b.x, a.y - b.y, a.z - b.z}; }
__device__ __forceinline__ P3 pcross(P3 a, P3 b) {
    return {a.y * b.z - a.z * b.y, a.z * b.x - a.x * b.z, a.x * b.y - a.y * b.x};
}
__device__ __forceinline__ v2f pdot(P3 a, P3 b) { return a.x * b.x + a.y * b.y + a.z * b.z; }
__device__ __forceinline__ v2f prsq(v2f q) {
    v2f r; r.x = __builtin_amdgcn_rsqf(q.x); r.y = __builtin_amdgcn_rsqf(q.y); return r;
}
__device__ __forceinline__ v2f pclip1(v2f x) {
    return __builtin_elementwise_min(__builtin_elementwise_max(x, mk2(-1.f, -1.f)),
                                     mk2(1.f, 1.f));
}

// Packed 4-term branchless asin, A&S 4.4.45 (|err| <= 6.8e-5).
__device__ __forceinline__ v2f fast_asin2(v2f x) {
    v2f a = __builtin_elementwise_abs(x);
    v2f p = mk2(-0.0187293f, -0.0187293f);
    p = p * a + mk2( 0.0742610f,  0.0742610f);
    p = p * a + mk2(-0.2121144f, -0.2121144f);
    p = p * a + mk2( 1.5707288f,  1.5707288f);
    v2f om = mk2(1.0f, 1.0f) - a;
    v2f sq; sq.x = __builtin_amdgcn_sqrtf(om.x); sq.y = __builtin_amdgcn_sqrtf(om.y);
    v2f r = mk2(1.57079632679f, 1.57079632679f) - sq * p;
    return __builtin_elementwise_copysign(r, x);
}

__device__ __forceinline__ P3 pack3(const float4 &a, const float4 &b) {
    return { mk2(a.x, b.x), mk2(a.y, b.y), mk2(a.z, b.z) };
}

// ============ COMPILE-TIME TABLES (verified rounds 13/14) ===================
// gseg[s]: u16 packed (i<<7)|j for segment s (row-major; padded with the
// safe segment (124,126)).
struct TabS { unsigned short v[NSEG_PAD]; };
constexpr TabS make_gseg() {
    TabS t{};
    int s = 0;
    for (int i = 0; i <= 124; ++i)
        for (int j = i + 2; j <= 126; ++j)
            t.v[s++] = (unsigned short)((i << 7) | j);
    for (; s < NSEG_PAD; ++s) t.v[s] = (unsigned short)((124 << 7) | 126);
    return t;
}
__device__ constexpr TabS g_gseg = make_gseg();

// ptab[k]: base0(13b) | base1<<13(13b) | m0<<26(2b) | m1<<28(2b). Pair
// {base, base+1} read via ds_read2_b32; bases anchored at the VALID slot
// (round-9 bug fix, correctness-verified rounds 10-14). Padded to 16384
// (pad entries = 0 -> harmless) so the NPF-deep prefetch never reads OOB.
struct TabP { unsigned v[PTAB_PAD]; };
constexpr TabP make_ptab() {
    TabP t{};
    for (int a = 0; a < 127; ++a) {
        for (int bb = a + 1; bb < 128; ++bb) {
            const int am1 = a - 1;
            const int s00 = 125 * am1 - (am1 * (am1 - 1)) / 2 + bb - a - 2; // (a-1,b-1)
            const int s10 = s00 + 125 - a;                                  // (a,  b-1)

            const bool v00 = (a >= 1) && (a <= 125) && (bb >= a + 2);
            const bool v01 = (a >= 1) && (a <= 125) && (bb <= 126);
            const bool v10 = (a <= 124) && (bb >= a + 3);
            const bool v11 = (a <= 124) && (bb <= 126) && (bb >= a + 2);

            const int base0 = v00 ? s00 : (v01 ? s00 + 1 : 0);
            const int base1 = v10 ? s10 : (v11 ? s10 + 1 : 0);
            const unsigned m0 = ((v00 || v01) ? 1u : 0u) | ((v00 && v01) ? 2u : 0u);
            const unsigned m1 = ((v10 || v11) ? 1u : 0u) | ((v10 && v11) ? 2u : 0u);

            const unsigned e = (unsigned)base0 | ((unsigned)base1 << 13)
                             | (m0 << 26) | (m1 << 28);
            t.v[127 * a + bb - 1] = e;   // (r,c) = (a,b), r < c
            t.v[127 * bb + a]     = e;   // (r,c) = (b,a), r > c
        }
    }
    return t;
}
__device__ constexpr TabP g_ptab = make_ptab();

// Writhe for TWO packed segments (x-lane = pa, y-lane = pb). Coordinates from
// float4 LDS. Sign via the exact identity
//   cross(p3-p2, p1-p0) . u0 = -(u3 x u2) . u0 = -n2 . u0.
// KEPT IN THE ROUND-8 INDEPENDENT FORM: rounds 10/11 measured that any
// cross-segment sliding-window sharing (serial m/q dependency) loses more to
// ILP collapse than it saves in instruction count (88.2 -> 96.3/98.5).
__device__ __forceinline__ v2f seg_writhe_pair(unsigned pa, unsigned pb,
                                               const float4* sp4) {
    int jA = (int)(pa & 127u), iA = (int)(pa >> 7);
    int jB = (int)(pb & 127u), iB = (int)(pb >> 7);

    float4 A0 = sp4[iA], A1 = sp4[iA + 1], A2 = sp4[jA], A3 = sp4[jA + 1];
    float4 B0 = sp4[iB], B1 = sp4[iB + 1], B2 = sp4[jB], B3 = sp4[jB + 1];

    P3 p0 = pack3(A0, B0);
    P3 p1 = pack3(A1, B1);
    P3 p2 = pack3(A2, B2);
    P3 p3 = pack3(A3, B3);

    P3 u0 = psub(p2, p0);
    P3 u1 = psub(p3, p0);
    P3 u2 = psub(p2, p1);
    P3 u3 = psub(p3, p1);

    P3 n0 = pcross(u0, u1);
    P3 n1 = pcross(u1, u3);
    P3 n2 = pcross(u3, u2);
    P3 n3 = pcross(u2, u0);

    v2f q0 = pdot(n0, n0);
    v2f q1 = pdot(n1, n1);
    v2f q2 = pdot(n2, n2);
    v2f q3 = pdot(n3, n3);

    v2f c0 = pclip1(pdot(n0, n1) * prsq(q0 * q1));
    v2f c1 = pclip1(pdot(n1, n2) * prsq(q1 * q2));
    v2f c2 = pclip1(pdot(n2, n3) * prsq(q2 * q3));
    v2f c3 = pclip1(pdot(n3, n0) * prsq(q3 * q0));

    v2f sd = pdot(n2, u0);     // = -(reference sd); sign folded below
    v2f omega = fast_asin2(c0) + fast_asin2(c1) + fast_asin2(c2) + fast_asin2(c3);

    v2f sgn;
    sgn.x = (sd.x > 0.f) ? -1.f : ((sd.x < 0.f) ? 1.f : 0.f);
    sgn.y = (sd.y > 0.f) ? -1.f : ((sd.y < 0.f) ? 1.f : 0.f);

    return omega * sgn * mk2(0.15915494309189535f, 0.15915494309189535f);
}

// ===================== main kernel: one block per batch =====================
// Round-15 change: gseg's 16 u16 loads/thread (indices t + k*512, k=0..15)
// are ALSO prefetched into registers before the barrier (round-14's ptab
// prefetch measured -4us for the same pattern). They complete under the
// xyz HBM latency + barrier drain, so Phase A's first pair-call starts with
// zero global-load stall. Cost: +8-16 VGPR (-> ~90 < 128 cap; occupancy
// unchanged, grid-limited at 4 waves/SIMD).
//   Phase A: round-8 independent packed-pair form (16 segments/thread, ILP).
//   Phase D: register-table paired ds_read2_b32 gathers (verified r14).
// LDS: sp4 2K + swr 32K = 34 KB. lb(512,2).
__global__ __launch_bounds__(BLOCK, 2) void writhe_main(
    const float* __restrict__ xyz,    // (B, 128, 3)
    float*       __restrict__ out)    // (B, 16256)
{
    __shared__ float4 sp4[NATOMS];
    __shared__ float  swr[NSEG_PAD];

    const int b = blockIdx.x;
    const int t = threadIdx.x;

    if (t < 3 * NATOMS) {
        float v = xyz[(size_t)b * (3 * NATOMS) + t];
        int a = t / 3, c = t - 3 * a;
        ((float*)&sp4[a])[c] = v;
    }

    // ---------- table register prefetch (issued before the barrier) ----------
    unsigned short sg[NSF];
    #pragma unroll
    for (int k = 0; k < NSF; ++k)
        sg[k] = g_gseg.v[t + k * BLOCK];     // Phase A indices are t + k*512

    unsigned pe[NPF];
    #pragma unroll
    for (int q = 0; q < NPF; ++q)
        pe[q] = g_ptab.v[t + q * BLOCK];     // t + 31*512 <= 16383 < PTAB_PAD

    __syncthreads();

    // ---------- Phase A: packed-pair writhe, 2 chains x 4 iterations ----------
    #pragma unroll
    for (int g = 0; g < 4; ++g) {
        const int sA = g * 2048 + t;           // = t + (4g)*512
        v2f w1 = seg_writhe_pair(sg[4 * g],     sg[4 * g + 1], sp4);
        v2f w2 = seg_writhe_pair(sg[4 * g + 2], sg[4 * g + 3], sp4);
        swr[sA]        = w1.x;
        swr[sA + 512]  = w1.y;
        swr[sA + 1024] = w2.x;
        swr[sA + 1536] = w2.y;
    }
    __syncthreads();

    // ---------- Phase D: pure-LDS paired gathers + coalesced store ----------
    // Lane-consecutive k: stride-1 bases across lanes (conflict-free).
    float* ob = out + (size_t)b * OUT_PER_B;
    #pragma unroll
    for (int q = 0; q < NPF; ++q) {
        const int k = t + q * BLOCK;
        if (q == NPF - 1 && k >= OUT_PER_B) break;   // only tail lanes exit

        const unsigned e = pe[q];
        const int s0 = (int)(e & 0x1FFFu);
        const int s1 = (int)((e >> 13) & 0x1FFFu);
        const unsigned vm = e >> 26;             // b0:a0  b1:a1  b2:c0  b3:c1

        const float* b0 = &swr[s0];
        const float* b1 = &swr[s1];
        const float a0 = b0[0], a1 = b0[1];      // one base, +0/+4 -> ds_read2_b32
        const float c0 = b1[0], c1 = b1[1];

        const float sum = ((vm & 1u) ? a0 : 0.f) + ((vm & 2u) ? a1 : 0.f)
                        + ((vm & 4u) ? c0 : 0.f) + ((vm & 8u) ? c1 : 0.f);

        __builtin_nontemporal_store(sum, ob + k);
    }
}

extern "C" void kernel_launch(void* const* d_in, const int* in_sizes, int n_in,
                              void* d_out, int out_size, void* d_ws, size_t ws_size,
                              hipStream_t stream) {
    const float* xyz = (const float*)d_in[0];
    float*       out = (float*)d_out;

    int B = in_sizes[0] / (NATOMS * 3);   // 512 for the reference shapes
    writhe_main<<<B, BLOCK, 0, stream>>>(xyz, out);   // single dispatch
}